// Round 8
// baseline (630.753 us; speedup 1.0000x reference)
//
#include <hip/hip_runtime.h>

// LightGCN via per-call CSR build + pure-gather layers + fused epilogue.
// k0: X1 = G(emb);  k1: X2 = G(X1);  k2: out = 0.25*(emb + X1 + X2 + G(X2))
// where G(x)[c] = sum_{e: col[e]=c} w[e] * x[row[e]].
// N = 500000, DIM = 64, E = 1.25M, fp32. int inputs arrive as int32.

#define NNODES   500000
#define DIMV     64
#define NEDGE    1250000
#define NELEM    (NNODES * DIMV)          // 32,000,000 floats
#define NELEM4   (NELEM / 4)
#define GRP      8                        // nodes per wave

#define SCAN_BLK   256
#define SCAN_ITEMS 8
#define SCAN_CHUNK (SCAN_BLK * SCAN_ITEMS)              // 2048
#define NB1 ((NNODES + SCAN_CHUNK - 1) / SCAN_CHUNK)    // 245 (<= 256)

// ======================= CSR build =======================

__global__ __launch_bounds__(256) void lgcn_zero_cnt(int* __restrict__ cnt)
{
    int i = blockIdx.x * blockDim.x + threadIdx.x;
    int stride = gridDim.x * blockDim.x;
    for (; i < NNODES; i += stride) cnt[i] = 0;
}

__global__ __launch_bounds__(256) void lgcn_hist(
    const int* __restrict__ col, int* __restrict__ cnt)
{
    int e = blockIdx.x * blockDim.x + threadIdx.x;
    if (e >= NEDGE) return;
    int c = col[e];
    if ((unsigned)c >= NNODES) return;       // insurance; never triggers
    atomicAdd(&cnt[c], 1);
}

__global__ __launch_bounds__(SCAN_BLK) void lgcn_scan1(
    const int* __restrict__ cnt, int* __restrict__ startv, int* __restrict__ bsum)
{
    __shared__ int sh[SCAN_BLK];
    int b = blockIdx.x;
    int base = b * SCAN_CHUNK;
    int tid = threadIdx.x;
    int v[SCAN_ITEMS];
    int local = 0;
    #pragma unroll
    for (int k = 0; k < SCAN_ITEMS; ++k) {
        int idx = base + tid * SCAN_ITEMS + k;
        v[k] = (idx < NNODES) ? cnt[idx] : 0;
        local += v[k];
    }
    sh[tid] = local;
    __syncthreads();
    for (int off = 1; off < SCAN_BLK; off <<= 1) {
        int x = (tid >= off) ? sh[tid - off] : 0;
        __syncthreads();
        sh[tid] += x;
        __syncthreads();
    }
    int run = (tid == 0) ? 0 : sh[tid - 1];
    if (tid == SCAN_BLK - 1) bsum[b] = sh[tid];
    #pragma unroll
    for (int k = 0; k < SCAN_ITEMS; ++k) {
        int idx = base + tid * SCAN_ITEMS + k;
        if (idx < NNODES) startv[idx] = run;
        run += v[k];
    }
}

__global__ __launch_bounds__(SCAN_BLK) void lgcn_scan2(int* __restrict__ bsum)
{
    __shared__ int sh[SCAN_BLK];
    int tid = threadIdx.x;
    sh[tid] = (tid < NB1) ? bsum[tid] : 0;
    __syncthreads();
    for (int off = 1; off < SCAN_BLK; off <<= 1) {
        int x = (tid >= off) ? sh[tid - off] : 0;
        __syncthreads();
        sh[tid] += x;
        __syncthreads();
    }
    if (tid < NB1) bsum[tid] = (tid == 0) ? 0 : sh[tid - 1];
}

__global__ __launch_bounds__(256) void lgcn_scan3(
    int* __restrict__ startv, int* __restrict__ cursor, const int* __restrict__ bsum)
{
    int i = blockIdx.x * blockDim.x + threadIdx.x;
    if (i < NNODES) {
        int s = startv[i] + bsum[i / SCAN_CHUNK];
        startv[i] = s;
        cursor[i] = s;
    }
    if (i == 0) startv[NNODES] = NEDGE;
}

__global__ __launch_bounds__(256) void lgcn_fill(
    const int* __restrict__ row, const int* __restrict__ col,
    const float* __restrict__ w, int* __restrict__ cursor, int2* __restrict__ pairs)
{
    int e = blockIdx.x * blockDim.x + threadIdx.x;
    if (e >= NEDGE) return;
    int c = col[e];
    if ((unsigned)c >= NNODES) return;       // must match lgcn_hist's guard
    int r = row[e];
    float wt = w[e];
    if ((unsigned)r >= NNODES) { r = 0; wt = 0.f; }   // insurance
    int p = atomicAdd(&cursor[c], 1);
    pairs[p] = make_int2(r, __float_as_int(wt));
}

// ======================= gather: 8 nodes / wave =======================
// MODE 0/1: xout[group] = gather sums (pure gather, minimal traffic)
// MODE 2:   outp[group] = 0.25 * (emb + x1 + x2 + gather sums)
template<int MODE>
__global__ __launch_bounds__(256) void lgcn_gather8(
    const float* __restrict__ src, float* __restrict__ xout,
    const float* __restrict__ emb, const float* __restrict__ x1,
    const float* __restrict__ x2, float* __restrict__ outp,
    const int2* __restrict__ pairs, const int* __restrict__ startv)
{
    constexpr int B = (MODE == 2) ? 8 : 16;   // gather MLP batch

    int t = blockIdx.x * blockDim.x + threadIdx.x;
    int wid = t >> 6;               // one wave per GRP nodes
    int lane = t & 63;              // one lane per dim
    int n0 = wid * GRP;
    if (n0 >= NNODES) return;

    // lane-parallel startv fetch: startv[n0 .. n0+GRP]
    int sv = (lane <= GRP) ? startv[n0 + lane] : 0;
    const int s0   = __shfl(sv, 0);
    const int b1   = __shfl(sv, 1) - s0;
    const int b2   = __shfl(sv, 2) - s0;
    const int b3   = __shfl(sv, 3) - s0;
    const int b4   = __shfl(sv, 4) - s0;
    const int b5   = __shfl(sv, 5) - s0;
    const int b6   = __shfl(sv, 6) - s0;
    const int b7   = __shfl(sv, 7) - s0;
    const int tote = __shfl(sv, 8) - s0;

    const size_t o0 = (size_t)n0 * DIMV + lane;

    // MODE 2: independent epilogue stream loads issue up front
    float ee[8], p1[8], p2[8];
    if (MODE == 2) {
        #pragma unroll
        for (int i = 0; i < 8; ++i) {
            ee[i] = emb[o0 + 64 * i];
            p1[i] = x1 [o0 + 64 * i];
            p2[i] = x2 [o0 + 64 * i];
        }
    }

    float m[8] = {0.f, 0.f, 0.f, 0.f, 0.f, 0.f, 0.f, 0.f};

    for (int base = 0; base < tote; base += 64) {
        int chunk = tote - base; if (chunk > 64) chunk = 64;
        int2 mp = (lane < chunk) ? pairs[s0 + base + lane] : make_int2(0, 0);
        for (int j = 0; j < chunk; j += B) {
            float v[B], wv[B];
            #pragma unroll
            for (int k = 0; k < B; ++k) {
                int jj = j + k;
                if (jj < chunk) {          // wave-uniform predicate
                    int r = __shfl(mp.x, jj);
                    wv[k] = __int_as_float(__shfl(mp.y, jj));
                    v[k]  = src[(size_t)r * DIMV + lane];   // independent gathers
                } else { v[k] = 0.f; wv[k] = 0.f; }
            }
            #pragma unroll
            for (int k = 0; k < B; ++k) {
                int jj = base + j + k;     // group-relative edge idx (uniform)
                if      (jj < b1) m[0] = fmaf(wv[k], v[k], m[0]);
                else if (jj < b2) m[1] = fmaf(wv[k], v[k], m[1]);
                else if (jj < b3) m[2] = fmaf(wv[k], v[k], m[2]);
                else if (jj < b4) m[3] = fmaf(wv[k], v[k], m[3]);
                else if (jj < b5) m[4] = fmaf(wv[k], v[k], m[4]);
                else if (jj < b6) m[5] = fmaf(wv[k], v[k], m[5]);
                else if (jj < b7) m[6] = fmaf(wv[k], v[k], m[6]);
                else              m[7] = fmaf(wv[k], v[k], m[7]);
            }
        }
    }

    if (MODE == 2) {
        #pragma unroll
        for (int i = 0; i < 8; ++i)
            outp[o0 + 64 * i] = (ee[i] + p1[i] + p2[i] + m[i]) * 0.25f;
    } else {
        #pragma unroll
        for (int i = 0; i < 8; ++i)
            xout[o0 + 64 * i] = m[i];
    }
}

// ======================= fallback: atomic scatter path =======================

__global__ __launch_bounds__(256) void lgcn_init(
    const float4* __restrict__ emb, float4* __restrict__ acc,
    float4* __restrict__ A, float4* __restrict__ B)
{
    int i = blockIdx.x * blockDim.x + threadIdx.x;
    int stride = gridDim.x * blockDim.x;
    for (; i < NELEM4; i += stride) {
        float4 v = emb[i];
        acc[i] = v;
        A[i]   = v;
        B[i]   = make_float4(0.f, 0.f, 0.f, 0.f);
    }
}

__global__ __launch_bounds__(256) void lgcn_scatter(
    const float* __restrict__ xcur, float* __restrict__ xnext,
    const int* __restrict__ row, const int* __restrict__ col,
    const float* __restrict__ w)
{
    int t = blockIdx.x * blockDim.x + threadIdx.x;
    int e = t >> 4;
    if (e >= NEDGE) return;
    int d = (t & 15) << 2;
    int r = row[e];
    int c = col[e];
    if ((unsigned)r >= NNODES || (unsigned)c >= NNODES) return;
    float wt = w[e];
    const float4 v = *reinterpret_cast<const float4*>(xcur + (size_t)r * DIMV + d);
    float* dst = xnext + (size_t)c * DIMV + d;
    atomicAdd(dst + 0, wt * v.x);
    atomicAdd(dst + 1, wt * v.y);
    atomicAdd(dst + 2, wt * v.z);
    atomicAdd(dst + 3, wt * v.w);
}

__global__ __launch_bounds__(256) void lgcn_addzero(
    float4* __restrict__ acc, const float4* __restrict__ X, float4* __restrict__ Y)
{
    int i = blockIdx.x * blockDim.x + threadIdx.x;
    int stride = gridDim.x * blockDim.x;
    for (; i < NELEM4; i += stride) {
        float4 a = acc[i];
        float4 x = X[i];
        a.x += x.x; a.y += x.y; a.z += x.z; a.w += x.w;
        acc[i] = a;
        Y[i] = make_float4(0.f, 0.f, 0.f, 0.f);
    }
}

__global__ __launch_bounds__(256) void lgcn_final(
    float4* __restrict__ acc, const float4* __restrict__ X)
{
    int i = blockIdx.x * blockDim.x + threadIdx.x;
    int stride = gridDim.x * blockDim.x;
    for (; i < NELEM4; i += stride) {
        float4 a = acc[i];
        float4 x = X[i];
        a.x = (a.x + x.x) * 0.25f;
        a.y = (a.y + x.y) * 0.25f;
        a.z = (a.z + x.z) * 0.25f;
        a.w = (a.w + x.w) * 0.25f;
        acc[i] = a;
    }
}

// ======================= launch =======================

extern "C" void kernel_launch(void* const* d_in, const int* in_sizes, int n_in,
                              void* d_out, int out_size, void* d_ws, size_t ws_size,
                              hipStream_t stream) {
    const float* emb  = (const float*)d_in[0];   // [N, 64] fp32
    const int*   eidx = (const int*)d_in[1];     // [2, E] int32
    const float* ew   = (const float*)d_in[2];   // [E] fp32
    float* acc = (float*)d_out;                  // [N, 64]

    const int* row = eidx;
    const int* col = eidx + NEDGE;

    // workspace layout (identical footprint to rounds 5-7)
    float* X1     = (float*)d_ws;                        // 128e6 B
    float* X2     = X1 + NELEM;                          // 128e6 B
    int2*  pairs  = (int2*)(X2 + NELEM);                 // 10e6 B (8-aligned)
    int*   startv = (int*)(pairs + NEDGE);               // (N+1)*4
    int*   cursor = startv + (NNODES + 1);               // N*4
    int*   bsum   = cursor + NNODES;                     // NB1*4
    const size_t needed = (size_t)2 * NELEM * 4 + (size_t)NEDGE * 8
                        + ((size_t)NNODES + 1) * 4 + (size_t)NNODES * 4 + (size_t)NB1 * 4;

    const int EDGE_BLOCKS = (NEDGE + 255) / 256;
    const int NODE_BLOCKS = (NNODES + 255) / 256;
    const int G8_BLOCKS   = ((NNODES / GRP) * 64 + 255) / 256;   // 62500 waves

    if (ws_size >= needed) {
        // ---- CSR build ----
        lgcn_zero_cnt<<<1954, 256, 0, stream>>>(cursor);
        lgcn_hist<<<EDGE_BLOCKS, 256, 0, stream>>>(col, cursor);
        lgcn_scan1<<<NB1, SCAN_BLK, 0, stream>>>(cursor, startv, bsum);
        lgcn_scan2<<<1, SCAN_BLK, 0, stream>>>(bsum);
        lgcn_scan3<<<NODE_BLOCKS, 256, 0, stream>>>(startv, cursor, bsum);
        lgcn_fill<<<EDGE_BLOCKS, 256, 0, stream>>>(row, col, ew, cursor, pairs);

        // ---- layers ----
        lgcn_gather8<0><<<G8_BLOCKS, 256, 0, stream>>>(
            emb, X1, nullptr, nullptr, nullptr, nullptr, pairs, startv);
        lgcn_gather8<1><<<G8_BLOCKS, 256, 0, stream>>>(
            X1, X2, nullptr, nullptr, nullptr, nullptr, pairs, startv);
        lgcn_gather8<2><<<G8_BLOCKS, 256, 0, stream>>>(
            X2, nullptr, emb, X1, X2, acc, pairs, startv);
    } else {
        // ---- fallback: proven atomic-scatter path ----
        float* A = (float*)d_ws;
        float* B = A + NELEM;
        const int SC_BLOCKS = (NEDGE * 16 + 255) / 256;
        lgcn_init<<<2048, 256, 0, stream>>>(
            (const float4*)emb, (float4*)acc, (float4*)A, (float4*)B);
        lgcn_scatter<<<SC_BLOCKS, 256, 0, stream>>>(A, B, row, col, ew);
        lgcn_addzero<<<2048, 256, 0, stream>>>((float4*)acc, (const float4*)B, (float4*)A);
        lgcn_scatter<<<SC_BLOCKS, 256, 0, stream>>>(B, A, row, col, ew);
        lgcn_addzero<<<2048, 256, 0, stream>>>((float4*)acc, (const float4*)A, (float4*)B);
        lgcn_scatter<<<SC_BLOCKS, 256, 0, stream>>>(A, B, row, col, ew);
        lgcn_final<<<2048, 256, 0, stream>>>((float4*)acc, (const float4*)B);
    }
}